// Round 6
// baseline (260.486 us; speedup 1.0000x reference)
//
#include <hip/hip_runtime.h>
#include <stdint.h>

#define EMB_DIM 192
#define CDIM 32
#define TDIM 4
#define N_Y 50000
#define N_X 32768
#define KNBR 8
#define ECNT (N_X*KNBR)  // 262144

// LDS row strides (shorts), odd-word -> low conflicts (proven R3-R5)
#define H1S 134
#define KS  33
#define ES  200

typedef __attribute__((ext_vector_type(8))) short bf16x8;
typedef __attribute__((ext_vector_type(4))) float f32x4;

static __device__ __forceinline__ short f2bf(float f){
  unsigned u = __float_as_uint(f);
  return (short)((u + 0x7FFFu) >> 16);
}
static __device__ __forceinline__ unsigned pk_bf16(float lo, float hi){
#if defined(__has_builtin)
#if __has_builtin(__builtin_amdgcn_cvt_pk_bf16_f32)
  typedef __attribute__((ext_vector_type(2))) __bf16 bf16x2_t;
  bf16x2_t v = __builtin_amdgcn_cvt_pk_bf16_f32(lo, hi);
  return *(unsigned*)&v;
#else
  return ((__float_as_uint(lo) + 0x7FFFu) >> 16) |
         ((((__float_as_uint(hi) + 0x7FFFu) >> 16)) << 16);
#endif
#else
  return ((__float_as_uint(lo) + 0x7FFFu) >> 16) |
         ((((__float_as_uint(hi) + 0x7FFFu) >> 16)) << 16);
#endif
}
static __device__ __forceinline__ float geluf(float x){
  float x2 = x * x;
  float u  = __builtin_fmaf(0.044715f, x2, 1.0f);
  float p  = x * -1.5957691216057308f;      // -2*0.7978845608
  float e  = __expf(p * u);                 // exp(-2t)
  return x * __builtin_amdgcn_rcpf(1.0f + e);
}

// ---- weights: W(K,N) fp32 -> W^T(N,K) bf16; W0 split into y-half / x-half of K ----
__global__ __launch_bounds__(256) void transpose_all(
    const float* __restrict__ W0, const float* __restrict__ W1,
    const float* __restrict__ W2, const float* __restrict__ W3,
    short* __restrict__ w0yt, short* __restrict__ w0xt,
    short* __restrict__ w1t, short* __restrict__ w2t, short* __restrict__ w3t){
  int id = blockIdx.x * 256 + threadIdx.x;
  if (id < 24576) {
    int n = id / 192, k = id - n * 192;
    w0yt[id] = f2bf(W0[k * 128 + n]);
  } else if (id < 49152) {
    int loc = id - 24576; int n = loc / 192, k = loc - n * 192;
    w0xt[loc] = f2bf(W0[(k + 192) * 128 + n]);
  } else if (id < 81920) {
    int loc = id - 49152; int n = loc / 128, k = loc - n * 128;
    w1t[loc] = f2bf(W1[k * 256 + n]);
  } else if (id < 114688) {
    int loc = id - 81920; int n = loc / 256, k = loc - n * 256;
    w2t[loc] = f2bf(W2[k * 128 + n]);
  } else if (id < 118784) {
    int loc = id - 114688; int n = loc / 128, k = loc - n * 128;
    w3t[loc] = f2bf(W3[k * 32 + n]);
  }
}

// ---- precompute: embed on the fly -> GEMM vs W0-half ----
__global__ __launch_bounds__(256, 2) void precompute_c(
    const float* __restrict__ ypts, const float* __restrict__ xpts,
    const short* __restrict__ w0yt, const short* __restrict__ w0xt,
    const float* __restrict__ b0,
    short* __restrict__ c_y, float* __restrict__ c_x)
{
  __shared__ __attribute__((aligned(16))) short s_e[64 * ES];
  const int tid = threadIdx.x;
  const bool isY = blockIdx.x < 782;
  const int row0 = isY ? blockIdx.x * 64 : (blockIdx.x - 782) * 64;
  const int wave = tid >> 6, lane = tid & 63;
  const int quad = lane >> 4, l15 = lane & 15;

  {
    const int r = tid >> 2, q = tid & 3;
    const int grow = row0 + r;
    const bool valid = isY ? (grow < N_Y) : true;
    const float* src = isY ? (ypts + (size_t)grow * 3) : (xpts + (size_t)grow * 3);
    float c[3] = {0.f, 0.f, 0.f};
    if (valid) { c[0] = src[0]; c[1] = src[1]; c[2] = src[2]; }
    #pragma unroll
    for (int j = 0; j < 24; ++j) {
      int p = q * 24 + j;
      int d = p >> 5, i = p & 31;
      float f = __expf(-0.28782313662425575f * (float)i);
      float s, co;
      __sincosf(c[d] * f, &s, &co);
      *(unsigned*)&s_e[r * ES + d * 64 + 2 * i] = pk_bf16(s, co);
    }
  }
  __syncthreads();

  const short* w0t = isY ? w0yt : w0xt;
  f32x4 acc[4][2];
  #pragma unroll
  for (int mt = 0; mt < 4; ++mt)
    #pragma unroll
    for (int nt = 0; nt < 2; ++nt) acc[mt][nt] = (f32x4){0.f, 0.f, 0.f, 0.f};
  #pragma unroll
  for (int ch = 0; ch < 6; ++ch) {
    bf16x8 a[4], b[2];
    #pragma unroll
    for (int mt = 0; mt < 4; ++mt)
      a[mt] = *(const bf16x8*)&s_e[(mt * 16 + l15) * ES + ch * 32 + quad * 8];
    #pragma unroll
    for (int nt = 0; nt < 2; ++nt)
      b[nt] = *(const bf16x8*)&w0t[(size_t)(wave * 32 + nt * 16 + l15) * 192 + ch * 32 + quad * 8];
    #pragma unroll
    for (int mt = 0; mt < 4; ++mt)
      #pragma unroll
      for (int nt = 0; nt < 2; ++nt)
        acc[mt][nt] = __builtin_amdgcn_mfma_f32_16x16x32_bf16(a[mt], b[nt], acc[mt][nt], 0, 0, 0);
  }
  #pragma unroll
  for (int nt = 0; nt < 2; ++nt) {
    int col = wave * 32 + nt * 16 + l15;
    float bias = isY ? 0.f : b0[col];
    #pragma unroll
    for (int mt = 0; mt < 4; ++mt)
      #pragma unroll
      for (int rg = 0; rg < 4; ++rg) {
        int grow = row0 + mt * 16 + quad * 4 + rg;
        if (isY) { if (grow < N_Y) c_y[(size_t)grow * 128 + col] = f2bf(acc[mt][nt][rg]); }
        else     { c_x[(size_t)grow * 128 + col] = acc[mt][nt][rg] + bias; }
      }
  }
}

// ---- edge kernel: gather-add-GELU -> L1 -> (L2 in two K-halves) -> L3 -> reduce ----
// region1 [0,17152): h2-half (64xH1S bf16), later kern (64xKS f32 = 8448)
// region2 [17152,34304): h1 (64xH1S bf16), later h3
__global__ __launch_bounds__(256, 4) void fused_edge(
    const short* __restrict__ c_y, const float* __restrict__ c_x,
    const int* __restrict__ nidx, const float* __restrict__ f_y,
    const short* __restrict__ w1t, const float* __restrict__ b1,
    const short* __restrict__ w2t, const float* __restrict__ b2,
    const short* __restrict__ w3t, const float* __restrict__ b3,
    float* __restrict__ out)
{
  __shared__ __attribute__((aligned(16))) char smem[34304];
  short* s_hh   = (short*)smem;                 // h2 half (64 x H1S)
  float* s_kern = (float*)smem;                 // aliases region1 after h2 reads done
  short* s_h1   = (short*)(smem + 17152);       // h1, later h3

  const int tid  = threadIdx.x;
  const int e0   = blockIdx.x * 64;
  const int wave = tid >> 6, lane = tid & 63;
  const int quad = lane >> 4, l15 = lane & 15;

  // ---- phase 0: h1 = gelu(c_y[idx] + c_x[e>>3]) ----
  {
    const int r = tid >> 2, q = tid & 3;
    const int idx = nidx[e0 + r];
    const uint4*  cyp = (const uint4*)(c_y + (size_t)idx * 128 + q * 32);
    const float4* cxp = (const float4*)(c_x + (size_t)((e0 + r) >> 3) * 128 + q * 32);
    uint4  cyv[4];
    float4 cxv[8];
    #pragma unroll
    for (int i = 0; i < 4; ++i) cyv[i] = cyp[i];
    #pragma unroll
    for (int i = 0; i < 8; ++i) cxv[i] = cxp[i];
    const float* cxa = (const float*)cxv;
    const unsigned* cya = (const unsigned*)cyv;
    unsigned pk[16];
    #pragma unroll
    for (int jj = 0; jj < 16; ++jj) {
      unsigned u = cya[jj];
      float lo = __uint_as_float(u << 16)         + cxa[2 * jj];
      float hi = __uint_as_float(u & 0xffff0000u) + cxa[2 * jj + 1];
      pk[jj] = pk_bf16(geluf(lo), geluf(hi));
    }
    uint4* dst = (uint4*)&s_h1[r * H1S + q * 32];
    #pragma unroll
    for (int jj = 0; jj < 4; ++jj)
      dst[jj] = *(uint4*)&pk[jj * 4];
  }
  __syncthreads();

  // ---------- layers 1+2 fused over two 128-col halves of h2 ----------
  f32x4 acc2[4][2];
  #pragma unroll
  for (int mt = 0; mt < 4; ++mt)
    #pragma unroll
    for (int nt = 0; nt < 2; ++nt) acc2[mt][nt] = (f32x4){0.f, 0.f, 0.f, 0.f};

  #pragma unroll
  for (int half = 0; half < 2; ++half) {
    // layer 1 partial: cols [half*128, half*128+128), wave owns 32 of them
    {
      f32x4 acc1[4][2];
      #pragma unroll
      for (int mt = 0; mt < 4; ++mt)
        #pragma unroll
        for (int nt = 0; nt < 2; ++nt) acc1[mt][nt] = (f32x4){0.f, 0.f, 0.f, 0.f};
      #pragma unroll
      for (int ch = 0; ch < 4; ++ch) {
        bf16x8 a[4], b[2];
        #pragma unroll
        for (int mt = 0; mt < 4; ++mt)
          a[mt] = *(const bf16x8*)&s_h1[(mt * 16 + l15) * H1S + ch * 32 + quad * 8];
        #pragma unroll
        for (int nt = 0; nt < 2; ++nt)
          b[nt] = *(const bf16x8*)&w1t[(size_t)(half * 128 + wave * 32 + nt * 16 + l15) * 128
                                       + ch * 32 + quad * 8];
        #pragma unroll
        for (int mt = 0; mt < 4; ++mt)
          #pragma unroll
          for (int nt = 0; nt < 2; ++nt)
            acc1[mt][nt] = __builtin_amdgcn_mfma_f32_16x16x32_bf16(a[mt], b[nt], acc1[mt][nt], 0, 0, 0);
      }
      #pragma unroll
      for (int nt = 0; nt < 2; ++nt) {
        int lcol = wave * 32 + nt * 16 + l15;           // 0..127 within half
        float bias = b1[half * 128 + lcol];
        #pragma unroll
        for (int mt = 0; mt < 4; ++mt)
          #pragma unroll
          for (int rg = 0; rg < 4; ++rg) {
            int row = mt * 16 + quad * 4 + rg;
            s_hh[row * H1S + lcol] = f2bf(geluf(acc1[mt][nt][rg] + bias));
          }
      }
    }
    __syncthreads();  // h2-half visible (also fences h1 reads of this half)

    // layer 2 partial-K accumulate: K chunk [half*128, half*128+128)
    #pragma unroll
    for (int ch = 0; ch < 4; ++ch) {
      bf16x8 a[4], b[2];
      #pragma unroll
      for (int mt = 0; mt < 4; ++mt)
        a[mt] = *(const bf16x8*)&s_hh[(mt * 16 + l15) * H1S + ch * 32 + quad * 8];
      #pragma unroll
      for (int nt = 0; nt < 2; ++nt)
        b[nt] = *(const bf16x8*)&w2t[(size_t)(wave * 32 + nt * 16 + l15) * 256
                                     + half * 128 + ch * 32 + quad * 8];
      #pragma unroll
      for (int mt = 0; mt < 4; ++mt)
        #pragma unroll
        for (int nt = 0; nt < 2; ++nt)
          acc2[mt][nt] = __builtin_amdgcn_mfma_f32_16x16x32_bf16(a[mt], b[nt], acc2[mt][nt], 0, 0, 0);
    }
    __syncthreads();  // half0: s_hh reads done -> half1 may overwrite; half1: fences before h3
  }

  // h3 epilogue -> region2 (h1 dead: last h1 read fenced by sync after layer1-half1)
  #pragma unroll
  for (int nt = 0; nt < 2; ++nt) {
    int col = wave * 32 + nt * 16 + l15;
    float bias = b2[col];
    #pragma unroll
    for (int mt = 0; mt < 4; ++mt)
      #pragma unroll
      for (int rg = 0; rg < 4; ++rg) {
        int row = mt * 16 + quad * 4 + rg;
        s_h1[row * H1S + col] = f2bf(geluf(acc2[mt][nt][rg] + bias));
      }
  }
  __syncthreads();   // h3 visible; s_hh reads done -> kern may overwrite region1

  // ---------- layer 3: 128 -> 32 linear (wave owns 16 rows) -> s_kern ----------
  {
    f32x4 acc3[2];
    acc3[0] = (f32x4){0.f, 0.f, 0.f, 0.f};
    acc3[1] = (f32x4){0.f, 0.f, 0.f, 0.f};
    #pragma unroll
    for (int ch = 0; ch < 4; ++ch) {
      bf16x8 a3 = *(const bf16x8*)&s_h1[(wave * 16 + l15) * H1S + ch * 32 + quad * 8];
      #pragma unroll
      for (int nt = 0; nt < 2; ++nt) {
        bf16x8 b3f = *(const bf16x8*)&w3t[(size_t)(nt * 16 + l15) * 128 + ch * 32 + quad * 8];
        acc3[nt] = __builtin_amdgcn_mfma_f32_16x16x32_bf16(a3, b3f, acc3[nt], 0, 0, 0);
      }
    }
    #pragma unroll
    for (int nt = 0; nt < 2; ++nt) {
      int col = nt * 16 + l15;
      float bias = b3[col];
      #pragma unroll
      for (int rg = 0; rg < 4; ++rg) {
        int row = wave * 16 + quad * 4 + rg;
        s_kern[row * KS + col] = acc3[nt][rg] + bias;
      }
    }
  }
  __syncthreads();

  // ---------- fused reduce ----------
  {
    const int xloc = tid >> 5;
    const int c    = tid & 31;
    float acc[TDIM] = {0.f, 0.f, 0.f, 0.f};
    const int ebase = xloc * 8;
    #pragma unroll
    for (int j = 0; j < KNBR; ++j) {
      float kv = s_kern[(ebase + j) * KS + c];
      int idx = nidx[e0 + ebase + j];
      const float* fp = f_y + (size_t)idx * CDIM + c;
      #pragma unroll
      for (int t = 0; t < TDIM; ++t)
        acc[t] += kv * fp[(size_t)t * N_Y * CDIM];
    }
    const int xg = blockIdx.x * 8 + xloc;
    #pragma unroll
    for (int t = 0; t < TDIM; ++t)
      out[((size_t)t * N_X + xg) * CDIM + c] = acc[t];
  }
}

extern "C" void kernel_launch(void* const* d_in, const int* in_sizes, int n_in,
                              void* d_out, int out_size, void* d_ws, size_t ws_size,
                              hipStream_t stream)
{
  const float* y   = (const float*)d_in[0];
  const float* x   = (const float*)d_in[1];
  const float* f_y = (const float*)d_in[2];
  const int*  nidx = (const int*)d_in[3];
  const float* W0 = (const float*)d_in[4];  const float* b0 = (const float*)d_in[5];
  const float* W1 = (const float*)d_in[6];  const float* b1 = (const float*)d_in[7];
  const float* W2 = (const float*)d_in[8];  const float* b2 = (const float*)d_in[9];
  const float* W3 = (const float*)d_in[10]; const float* b3 = (const float*)d_in[11];

  char* ws = (char*)d_ws;
  short* c_y  = (short*)(ws + 0);           // 50000*128*2  = 12,800,000
  float* c_x  = (float*)(ws + 12800000);    // 32768*128*4  = 16,777,216
  short* w0yt = (short*)(ws + 29577216);
  short* w0xt = (short*)(ws + 29626368);
  short* w1t  = (short*)(ws + 29675520);
  short* w2t  = (short*)(ws + 29741056);
  short* w3t  = (short*)(ws + 29806592);

  hipLaunchKernelGGL(transpose_all, dim3((118784 + 255) / 256), dim3(256), 0, stream,
                     W0, W1, W2, W3, w0yt, w0xt, w1t, w2t, w3t);
  hipLaunchKernelGGL(precompute_c, dim3(782 + 512), dim3(256), 0, stream,
                     y, x, w0yt, w0xt, b0, c_y, c_x);
  hipLaunchKernelGGL(fused_edge, dim3(ECNT / 64), dim3(256), 0, stream,
                     c_y, c_x, nidx, f_y, w1t, b1, w2t, b2, w3t, b3, (float*)d_out);
}